// Round 5
// baseline (882.571 us; speedup 1.0000x reference)
//
#include <hip/hip_runtime.h>
#include <hip/hip_bf16.h>
#include <math.h>

typedef __bf16 bf16x8 __attribute__((ext_vector_type(8)));
typedef float f32x4 __attribute__((ext_vector_type(4)));
typedef float f32x16 __attribute__((ext_vector_type(16)));

#define B_DIM 8
#define S_DIM 512
#define D_DIM 768
#define NC 8921
#define N_PAD 8960
#define TILE_N 64
#define N_TILES 140
#define NKCH 24            // K chunks of 32 elements (64 B)
#define MASK_BYTES 16384

typedef const __attribute__((address_space(1))) void* gas1_t;
typedef __attribute__((address_space(3))) void* las3_t;

// ---- mask prep: sniff dtype (bool8 / int32 / float32) and emit 0/-inf bias
__global__ void prep_mask_kernel(const unsigned char* __restrict__ raw, float* __restrict__ bias) {
  __shared__ int s_ms, s_f32;
  int tid = threadIdx.x;
  if (tid == 0) { s_ms = 0; s_f32 = 0; }
  __syncthreads();
  int ms = 0, f32c = 0;
  for (int i = tid; i < B_DIM * S_DIM; i += 256) {
    unsigned char c = raw[i];
    if ((i & 3) != 0 && c != 0) ms++;
    if ((i & 3) == 3 && c == 0x3F) f32c++;
  }
  atomicAdd(&s_ms, ms);
  atomicAdd(&s_f32, f32c);
  __syncthreads();
  int mode = (s_ms == 0) ? 0 : ((s_f32 > 500) ? 2 : 1);
  for (int i = tid; i < B_DIM * S_DIM; i += 256) {
    bool m;
    if (mode == 0)      m = ((const int*)raw)[i] != 0;
    else if (mode == 1) m = raw[i] != 0;
    else                m = ((const float*)raw)[i] != 0.0f;
    bias[i] = m ? 0.0f : -INFINITY;
  }
}

// ---- f32 -> bf16 conversion (times scale) with zero padding past nvalid
__global__ void cvt_kernel(const float* __restrict__ src, __bf16* __restrict__ dst,
                           long nvalid, float scale) {
  long i = ((long)blockIdx.x * blockDim.x + threadIdx.x) * 8;
  bf16x8 o;
  if (i + 8 <= nvalid) {
    float4 a = *reinterpret_cast<const float4*>(src + i);
    float4 b = *reinterpret_cast<const float4*>(src + i + 4);
    o[0] = (__bf16)(a.x * scale); o[1] = (__bf16)(a.y * scale);
    o[2] = (__bf16)(a.z * scale); o[3] = (__bf16)(a.w * scale);
    o[4] = (__bf16)(b.x * scale); o[5] = (__bf16)(b.y * scale);
    o[6] = (__bf16)(b.z * scale); o[7] = (__bf16)(b.w * scale);
  } else {
#pragma unroll
    for (int j = 0; j < 8; ++j) o[j] = (__bf16)0.0f;
  }
  *reinterpret_cast<bf16x8*>(dst + i) = o;
}

// ---- main fused kernel: 16 waves, per-wave-private 32-S slice staged via
//      global_load_lds (counted vmcnt, no barriers in K-loop), 32x32x16 MFMA
//      with E as A-operand so softmax reduces in-register.
__launch_bounds__(1024, 4)
__global__ void fused_kernel(const __bf16* __restrict__ Eb, const __bf16* __restrict__ Qb,
                             const __bf16* __restrict__ Wb, const float* __restrict__ bias,
                             float* __restrict__ out) {
  // staging: 2 buffers x (16 waves x 2KB) = 64KB; epilogue reuses as transpose pad
  __shared__ __attribute__((aligned(16))) char smem[67584];   // 16 waves x 32x33 f32
  __shared__ float redM[16][64];
  __shared__ float redS[16][64];
  __shared__ float redP[16][64];
  __shared__ float gmaxL[64];
  __shared__ float invL[64];

  const int bid = blockIdx.x;
  const int b = bid & 7;                  // batch == XCD -> E slice L2-resident
  const int nbase = (bid >> 3) * TILE_N;
  const int tid = threadIdx.x;
  const int lane = tid & 63;
  const int w = tid >> 6;                 // wave id: owns S rows [w*32, w*32+32)
  const int l31 = lane & 31;
  const int hi = lane >> 5;

  f32x16 accL[2], accG[2];
#pragma unroll
  for (int ct = 0; ct < 2; ++ct)
#pragma unroll
    for (int r = 0; r < 16; ++r) { accL[ct][r] = 0.f; accG[ct][r] = 0.f; }

  // ---- staging addressing (rule 21: linear LDS dest, inverse-swizzled source)
  // instr j covers rows j*16..j*16+15 of the wave slice; lane -> row j*16+(lane>>2),
  // 16B slot (lane&3) ^ ((row>>1)&3). Note ((16+s)>>1)&3 == ((s>>1)&3), so one base.
  const int s0 = lane >> 2;
  const char* eSrc = (const char*)Eb
      + ((size_t)b * S_DIM + (size_t)w * 32 + s0) * (D_DIM * 2)
      + (((lane & 3) ^ ((s0 >> 1) & 3)) * 16);
  const int ldsD = w * 2048 + lane * 16;

  // A-fragment (E) ds_read offsets: row=l31, k-slot = kh*2+hi, swizzled
  int eOff[2];
#pragma unroll
  for (int kh = 0; kh < 2; ++kh)
    eOff[kh] = w * 2048 + l31 * 64 + ((((kh << 1) | hi) ^ ((l31 >> 1) & 3)) << 4);

  // B-fragment (Q/CW) pointers: col = code = nbase + ct*32 + l31, k-base = hi*8
  const __bf16* qP0 = Qb + (size_t)(nbase + l31) * D_DIM + hi * 8;
  const __bf16* cP0 = Wb + (size_t)(nbase + l31) * D_DIM + hi * 8;

  bf16x8 bq[2][2], bc[2][2], bqn[2][2], bcn[2][2];

#define STAGE(T) {                                                                  \
    char* d_ = smem + (((T) & 1) ? 32768 : 0) + ldsD;                               \
    const char* s_ = eSrc + (T) * 64;                                               \
    __builtin_amdgcn_global_load_lds((gas1_t)(s_),          (las3_t)(d_),        16, 0, 0); \
    __builtin_amdgcn_global_load_lds((gas1_t)(s_ + 24576),  (las3_t)(d_ + 1024), 16, 0, 0); }

#define PREF(T, BQ, BC) {                                                           \
    _Pragma("unroll")                                                               \
    for (int ct = 0; ct < 2; ++ct) {                                                \
      const __bf16* qp = qP0 + (size_t)ct * 32 * D_DIM + (T) * 32;                  \
      const __bf16* cp = cP0 + (size_t)ct * 32 * D_DIM + (T) * 32;                  \
      BQ[ct][0] = *(const bf16x8*)(qp);                                             \
      BQ[ct][1] = *(const bf16x8*)(qp + 16);                                        \
      BC[ct][0] = *(const bf16x8*)(cp);                                             \
      BC[ct][1] = *(const bf16x8*)(cp + 16); } }

#define COMP(T, BQ, BC) {                                                           \
    const char* buf_ = smem + (((T) & 1) ? 32768 : 0);                              \
    _Pragma("unroll")                                                               \
    for (int kh = 0; kh < 2; ++kh) {                                                \
      bf16x8 ef = *(const bf16x8*)(buf_ + eOff[kh]);                                \
      accL[0] = __builtin_amdgcn_mfma_f32_32x32x16_bf16(ef, BQ[0][kh], accL[0], 0, 0, 0); \
      accG[0] = __builtin_amdgcn_mfma_f32_32x32x16_bf16(ef, BC[0][kh], accG[0], 0, 0, 0); \
      accL[1] = __builtin_amdgcn_mfma_f32_32x32x16_bf16(ef, BQ[1][kh], accL[1], 0, 0, 0); \
      accG[1] = __builtin_amdgcn_mfma_f32_32x32x16_bf16(ef, BC[1][kh], accG[1], 0, 0, 0); } }

  // prologue
  STAGE(0)
  PREF(0, bq, bc)

#pragma unroll 2
  for (int kt = 0; kt < NKCH - 1; ++kt) {
    PREF(kt + 1, bqn, bcn)
    STAGE(kt + 1)
    asm volatile("s_waitcnt vmcnt(10)" ::: "memory");  // drains stage(kt)+B(kt); leaves kt+1 in flight
    __builtin_amdgcn_sched_barrier(0);
    COMP(kt, bq, bc)
#pragma unroll
    for (int ct = 0; ct < 2; ++ct)
#pragma unroll
      for (int kh = 0; kh < 2; ++kh) { bq[ct][kh] = bqn[ct][kh]; bc[ct][kh] = bcn[ct][kh]; }
  }
  asm volatile("s_waitcnt vmcnt(0)" ::: "memory");
  __builtin_amdgcn_sched_barrier(0);
  COMP(NKCH - 1, bq, bc)
#undef STAGE
#undef PREF
#undef COMP

  // ---- epilogue: lane holds D[S=rowof(r,hi)+w*32][code=ct*32+l31]
  // bias per S-row (16 regs)
  float bv[16];
#pragma unroll
  for (int r = 0; r < 16; ++r)
    bv[r] = bias[b * S_DIM + w * 32 + (r & 3) + 8 * (r >> 2) + 4 * hi];

  // row... per-code max over this wave's 32 S rows: in-lane over 16 regs + xor32
#pragma unroll
  for (int ct = 0; ct < 2; ++ct) {
    float m = -INFINITY;
#pragma unroll
    for (int r = 0; r < 16; ++r) {
      float v = accL[ct][r] + bv[r];
      accL[ct][r] = v;
      m = fmaxf(m, v);
    }
    m = fmaxf(m, __shfl_xor(m, 32));
    if (hi == 0) redM[w][ct * 32 + l31] = m;
  }
  __syncthreads();

  if (tid < 64) {
    float m = redM[0][tid];
#pragma unroll
    for (int ww = 1; ww < 16; ++ww) m = fmaxf(m, redM[ww][tid]);
    gmaxL[tid] = m;
  }
  __syncthreads();

#pragma unroll
  for (int ct = 0; ct < 2; ++ct) {
    float gm = gmaxL[ct * 32 + l31];
    float s = 0.f, g = 0.f;
#pragma unroll
    for (int r = 0; r < 16; ++r) {
      float p = __expf(accL[ct][r] - gm);
      accL[ct][r] = p;
      s += p;
      g += p * accG[ct][r];
    }
    s += __shfl_xor(s, 32);
    g += __shfl_xor(g, 32);
    if (hi == 0) { redS[w][ct * 32 + l31] = s; redP[w][ct * 32 + l31] = g; }
  }
  __syncthreads();

  if (tid < 64) {
    float s = redS[0][tid], g = redP[0][tid];
#pragma unroll
    for (int ww = 1; ww < 16; ++ww) { s += redS[ww][tid]; g += redP[ww][tid]; }
    float iv = 1.0f / s;
    invL[tid] = iv;
    int gn = nbase + tid;
    if (gn < NC) out[(size_t)b * NC + gn] = g * iv;
  }
  __syncthreads();

  // ---- weights store: transpose via per-wave [32 code][33] padded LDS tile
  float* outW = out + (size_t)B_DIM * NC;
  float* sp = (float*)smem + w * (32 * 33);
#pragma unroll
  for (int ct = 0; ct < 2; ++ct) {
    float iv = invL[ct * 32 + l31];
#pragma unroll
    for (int r = 0; r < 16; ++r) {
      int rowloc = (r & 3) + 8 * (r >> 2) + 4 * hi;
      sp[l31 * 33 + rowloc] = accL[ct][r] * iv;   // conflict-free: bank=(l31+rowloc)%32
    }
#pragma unroll
    for (int i = 0; i < 16; ++i) {
      int code = i * 2 + hi;
      float v = sp[code * 33 + l31];
      int gn = nbase + ct * 32 + code;
      if (gn < NC)
        outW[((size_t)b * NC + gn) * S_DIM + w * 32 + l31] = v;  // 128B segments
    }
  }
}

// ---- fallback (ws too small for bf16 preconversion): f32 reg-staging path
__launch_bounds__(512, 2)
__global__ void fused_fallback(const float* __restrict__ E32, const float* __restrict__ Q32,
                               const float* __restrict__ W32,
                               const float* __restrict__ bias, float* __restrict__ out) {
  __shared__ __attribute__((aligned(16))) __bf16 sE[S_DIM][40];
  __shared__ __attribute__((aligned(16))) __bf16 sQ[TILE_N][40];
  __shared__ __attribute__((aligned(16))) __bf16 sC[TILE_N][40];
  __shared__ float redA[4][TILE_N];
  __shared__ float redB[4][TILE_N];

  const int bid = blockIdx.x;
  const int b = bid & 7;
  const int nbase = (bid >> 3) * TILE_N;
  const int tid = threadIdx.x;
  const int lane = tid & 63;
  const int wave = tid >> 6;
  const int wm = wave >> 2, wsl = wave & 3;
  const int l15 = lane & 15, lg = lane >> 4;

  f32x4 accL[2][8], accG[2][8];
  f32x4 zero = {0.f, 0.f, 0.f, 0.f};
#pragma unroll
  for (int mt = 0; mt < 2; ++mt)
#pragma unroll
    for (int nt = 0; nt < 8; ++nt) { accL[mt][nt] = zero; accG[mt][nt] = zero; }

  const size_t eBase = (size_t)b * S_DIM * D_DIM;

  for (int kt = 0; kt < 24; ++kt) {
    const int k0 = kt * 32;
#pragma unroll
    for (int i = 0; i < 4; ++i) {
      int task = tid + i * 512;
      int s = task >> 2, dg = task & 3;
      const float* sp = E32 + eBase + (size_t)s * D_DIM + k0 + dg * 8;
      float4 a = *reinterpret_cast<const float4*>(sp);
      float4 c = *reinterpret_cast<const float4*>(sp + 4);
      bf16x8 v;
      v[0] = (__bf16)a.x; v[1] = (__bf16)a.y; v[2] = (__bf16)a.z; v[3] = (__bf16)a.w;
      v[4] = (__bf16)c.x; v[5] = (__bf16)c.y; v[6] = (__bf16)c.z; v[7] = (__bf16)c.w;
      *reinterpret_cast<bf16x8*>(&sE[s][dg * 8]) = v;
    }
    {
      int t = tid & 255;
      int r = t >> 2, dg = t & 3;
      int gr = nbase + r;
      bf16x8 v;
      if (gr < NC) {
        const float* sp = ((tid < 256) ? Q32 : W32) + (size_t)gr * D_DIM + k0 + dg * 8;
        float4 a = *reinterpret_cast<const float4*>(sp);
        float4 c = *reinterpret_cast<const float4*>(sp + 4);
        v[0] = (__bf16)a.x; v[1] = (__bf16)a.y; v[2] = (__bf16)a.z; v[3] = (__bf16)a.w;
        v[4] = (__bf16)c.x; v[5] = (__bf16)c.y; v[6] = (__bf16)c.z; v[7] = (__bf16)c.w;
      } else {
#pragma unroll
        for (int j = 0; j < 8; ++j) v[j] = (__bf16)0.0f;
      }
      __bf16* dst = (tid < 256) ? &sQ[r][dg * 8] : &sC[r][dg * 8];
      *reinterpret_cast<bf16x8*>(dst) = v;
    }
    __syncthreads();

    bf16x8 qf0 = *reinterpret_cast<const bf16x8*>(&sQ[wm * 32 + l15][lg * 8]);
    bf16x8 qf1 = *reinterpret_cast<const bf16x8*>(&sQ[wm * 32 + 16 + l15][lg * 8]);
    bf16x8 cf0 = *reinterpret_cast<const bf16x8*>(&sC[wm * 32 + l15][lg * 8]);
    bf16x8 cf1 = *reinterpret_cast<const bf16x8*>(&sC[wm * 32 + 16 + l15][lg * 8]);

#pragma unroll
    for (int nt = 0; nt < 8; ++nt) {
      bf16x8 bf = *reinterpret_cast<const bf16x8*>(&sE[wsl * 128 + nt * 16 + l15][lg * 8]);
      accL[0][nt] = __builtin_amdgcn_mfma_f32_16x16x32_bf16(qf0, bf, accL[0][nt], 0, 0, 0);
      accL[1][nt] = __builtin_amdgcn_mfma_f32_16x16x32_bf16(qf1, bf, accL[1][nt], 0, 0, 0);
      accG[0][nt] = __builtin_amdgcn_mfma_f32_16x16x32_bf16(cf0, bf, accG[0][nt], 0, 0, 0);
      accG[1][nt] = __builtin_amdgcn_mfma_f32_16x16x32_bf16(cf1, bf, accG[1][nt], 0, 0, 0);
    }
    __syncthreads();
  }

  const float scale = 0.036084391824351615f;
  const float* brow = bias + b * S_DIM;
  float bval[8];
#pragma unroll
  for (int nt = 0; nt < 8; ++nt) bval[nt] = brow[wsl * 128 + nt * 16 + l15];

  float rmax[2][4];
#pragma unroll
  for (int mt = 0; mt < 2; ++mt)
#pragma unroll
    for (int r = 0; r < 4; ++r) rmax[mt][r] = -INFINITY;
#pragma unroll
  for (int mt = 0; mt < 2; ++mt)
#pragma unroll
    for (int nt = 0; nt < 8; ++nt)
#pragma unroll
      for (int r = 0; r < 4; ++r) {
        float v = accL[mt][nt][r] * scale + bval[nt];
        accL[mt][nt][r] = v;
        rmax[mt][r] = fmaxf(rmax[mt][r], v);
      }
#pragma unroll
  for (int mt = 0; mt < 2; ++mt)
#pragma unroll
    for (int r = 0; r < 4; ++r) {
      float v = rmax[mt][r];
      v = fmaxf(v, __shfl_xor(v, 1)); v = fmaxf(v, __shfl_xor(v, 2));
      v = fmaxf(v, __shfl_xor(v, 4)); v = fmaxf(v, __shfl_xor(v, 8));
      rmax[mt][r] = v;
    }
  if (l15 == 0) {
#pragma unroll
    for (int mt = 0; mt < 2; ++mt)
#pragma unroll
      for (int r = 0; r < 4; ++r) redA[wsl][wm * 32 + mt * 16 + lg * 4 + r] = rmax[mt][r];
  }
  __syncthreads();
  float gmax[2][4];
#pragma unroll
  for (int mt = 0; mt < 2; ++mt)
#pragma unroll
    for (int r = 0; r < 4; ++r) {
      int row = wm * 32 + mt * 16 + lg * 4 + r;
      gmax[mt][r] = fmaxf(fmaxf(redA[0][row], redA[1][row]), fmaxf(redA[2][row], redA[3][row]));
    }
  __syncthreads();
  float rsum[2][4], pg[2][4];
#pragma unroll
  for (int mt = 0; mt < 2; ++mt)
#pragma unroll
    for (int r = 0; r < 4; ++r) { rsum[mt][r] = 0.f; pg[mt][r] = 0.f; }
#pragma unroll
  for (int mt = 0; mt < 2; ++mt)
#pragma unroll
    for (int nt = 0; nt < 8; ++nt)
#pragma unroll
      for (int r = 0; r < 4; ++r) {
        float p = __expf(accL[mt][nt][r] - gmax[mt][r]);
        accL[mt][nt][r] = p;
        rsum[mt][r] += p;
        pg[mt][r] += p * accG[mt][nt][r];
      }
#pragma unroll
  for (int mt = 0; mt < 2; ++mt)
#pragma unroll
    for (int r = 0; r < 4; ++r) {
      float s1 = rsum[mt][r], s2 = pg[mt][r];
      s1 += __shfl_xor(s1, 1); s1 += __shfl_xor(s1, 2); s1 += __shfl_xor(s1, 4); s1 += __shfl_xor(s1, 8);
      s2 += __shfl_xor(s2, 1); s2 += __shfl_xor(s2, 2); s2 += __shfl_xor(s2, 4); s2 += __shfl_xor(s2, 8);
      rsum[mt][r] = s1; pg[mt][r] = s2;
    }
  if (l15 == 0) {
#pragma unroll
    for (int mt = 0; mt < 2; ++mt)
#pragma unroll
      for (int r = 0; r < 4; ++r) {
        int row = wm * 32 + mt * 16 + lg * 4 + r;
        redA[wsl][row] = rsum[mt][r];
        redB[wsl][row] = pg[mt][r];
      }
  }
  __syncthreads();
  float inv[2][4];
#pragma unroll
  for (int mt = 0; mt < 2; ++mt)
#pragma unroll
    for (int r = 0; r < 4; ++r) {
      int row = wm * 32 + mt * 16 + lg * 4 + r;
      float st = redA[0][row] + redA[1][row] + redA[2][row] + redA[3][row];
      inv[mt][r] = 1.0f / st;
    }
  float* outW = out + (size_t)B_DIM * NC;
#pragma unroll
  for (int mt = 0; mt < 2; ++mt)
#pragma unroll
    for (int r = 0; r < 4; ++r) {
      int gn = nbase + wm * 32 + mt * 16 + lg * 4 + r;
      if (gn < NC) {
        size_t base = ((size_t)b * NC + gn) * S_DIM + wsl * 128 + l15;
        float iv = inv[mt][r];
#pragma unroll
        for (int nt = 0; nt < 8; ++nt) outW[base + nt * 16] = accL[mt][nt][r] * iv;
      }
    }
  if (wsl == 0 && l15 == 0) {
#pragma unroll
    for (int mt = 0; mt < 2; ++mt)
#pragma unroll
      for (int r = 0; r < 4; ++r) {
        int row = wm * 32 + mt * 16 + lg * 4 + r;
        int gn = nbase + row;
        if (gn < NC) {
          float tot = redB[0][row] + redB[1][row] + redB[2][row] + redB[3][row];
          out[(size_t)b * NC + gn] = tot * inv[mt][r];
        }
      }
  }
}

extern "C" void kernel_launch(void* const* d_in, const int* in_sizes, int n_in,
                              void* d_out, int out_size, void* d_ws, size_t ws_size,
                              hipStream_t stream) {
  const float* E32 = (const float*)d_in[0];
  const unsigned char* mraw = (const unsigned char*)d_in[1];
  const float* Q32 = (const float*)d_in[2];
  const float* W32 = (const float*)d_in[3];
  float* out = (float*)d_out;

  char* ws = (char*)d_ws;
  float* bias = (float*)ws;
  __bf16* Eb = (__bf16*)(ws + MASK_BYTES);
  __bf16* Qb = (__bf16*)(ws + MASK_BYTES + (size_t)B_DIM * S_DIM * D_DIM * 2);
  __bf16* Wb = (__bf16*)((char*)Qb + (size_t)N_PAD * D_DIM * 2);
  size_t need = MASK_BYTES + (size_t)B_DIM * S_DIM * D_DIM * 2 + 2 * (size_t)N_PAD * D_DIM * 2;
  int preconv = (ws_size >= need) ? 1 : 0;

  prep_mask_kernel<<<1, 256, 0, stream>>>(mraw, bias);

  if (preconv) {
    long nE = (long)B_DIM * S_DIM * D_DIM;
    cvt_kernel<<<(int)(nE / 8 / 256), 256, 0, stream>>>(E32, Eb, nE, 1.0f);
    long nQ = (long)NC * D_DIM;
    long nQp = (long)N_PAD * D_DIM;
    // fold 1/sqrt(D) into Q
    cvt_kernel<<<(int)(nQp / 8 / 256), 256, 0, stream>>>(Q32, Qb, nQ, 0.036084391824351615f);
    cvt_kernel<<<(int)(nQp / 8 / 256), 256, 0, stream>>>(W32, Wb, nQ, 1.0f);
    fused_kernel<<<N_TILES * B_DIM, 1024, 0, stream>>>(Eb, Qb, Wb, bias, out);
  } else {
    fused_fallback<<<N_TILES * B_DIM, 512, 0, stream>>>(E32, Q32, W32, bias, out);
  }
}

// Round 6
// 260.595 us; speedup vs baseline: 3.3868x; 3.3868x over previous
//
#include <hip/hip_runtime.h>
#include <hip/hip_bf16.h>
#include <math.h>

typedef __bf16 bf16x8 __attribute__((ext_vector_type(8)));
typedef float f32x4 __attribute__((ext_vector_type(4)));

#define B_DIM 8
#define S_DIM 512
#define D_DIM 768
#define NC 8921
#define N_PAD 8960
#define TILE_N 32
#define N_TILES 280
#define NKCH 24
#define MASK_BYTES 16384
#define SWZ(a) ((a) ^ ((((unsigned)(a)) >> 3) & 0x30))

typedef const __attribute__((address_space(1))) void* gas1_t;
typedef __attribute__((address_space(3))) void* las3_t;

// ---- mask prep: sniff dtype (bool8 / int32 / float32) and emit 0/-inf bias
__global__ void prep_mask_kernel(const unsigned char* __restrict__ raw, float* __restrict__ bias) {
  __shared__ int s_ms, s_f32;
  int tid = threadIdx.x;
  if (tid == 0) { s_ms = 0; s_f32 = 0; }
  __syncthreads();
  int ms = 0, f32c = 0;
  for (int i = tid; i < B_DIM * S_DIM; i += 256) {
    unsigned char c = raw[i];
    if ((i & 3) != 0 && c != 0) ms++;
    if ((i & 3) == 3 && c == 0x3F) f32c++;
  }
  atomicAdd(&s_ms, ms);
  atomicAdd(&s_f32, f32c);
  __syncthreads();
  int mode = (s_ms == 0) ? 0 : ((s_f32 > 500) ? 2 : 1);
  for (int i = tid; i < B_DIM * S_DIM; i += 256) {
    bool m;
    if (mode == 0)      m = ((const int*)raw)[i] != 0;
    else if (mode == 1) m = raw[i] != 0;
    else                m = ((const float*)raw)[i] != 0.0f;
    bias[i] = m ? 0.0f : -INFINITY;
  }
}

// ---- f32 -> bf16 conversion (times scale) with zero padding past nvalid
__global__ void cvt_kernel(const float* __restrict__ src, __bf16* __restrict__ dst,
                           long nvalid, float scale) {
  long i = ((long)blockIdx.x * blockDim.x + threadIdx.x) * 8;
  bf16x8 o;
  if (i + 8 <= nvalid) {
    float4 a = *reinterpret_cast<const float4*>(src + i);
    float4 b = *reinterpret_cast<const float4*>(src + i + 4);
    o[0] = (__bf16)(a.x * scale); o[1] = (__bf16)(a.y * scale);
    o[2] = (__bf16)(a.z * scale); o[3] = (__bf16)(a.w * scale);
    o[4] = (__bf16)(b.x * scale); o[5] = (__bf16)(b.y * scale);
    o[6] = (__bf16)(b.z * scale); o[7] = (__bf16)(b.w * scale);
  } else {
#pragma unroll
    for (int j = 0; j < 8; ++j) o[j] = (__bf16)0.0f;
  }
  *reinterpret_cast<bf16x8*>(dst + i) = o;
}

// ---- main fused kernel: r2 structure with TILE_N=32 so a wave fits in 128
//      unified regs -> 2 blocks/CU (4 waves/SIMD) decorrelated latency hiding.
__launch_bounds__(512, 4)
__global__ void fused_kernel(const __bf16* __restrict__ Eb, const __bf16* __restrict__ Qb,
                             const __bf16* __restrict__ Wb, const float* __restrict__ bias,
                             float* __restrict__ out) {
  __shared__ __attribute__((aligned(16))) char smem[2 * 32768];
  __shared__ float redA[4][TILE_N];
  __shared__ float redB[4][TILE_N];

  const int bid = blockIdx.x;
  const int b = bid & 7;                 // batch == XCD -> E slice L2-resident
  const int nbase = (bid >> 3) * TILE_N;
  const int tid = threadIdx.x;
  const int lane = tid & 63;
  const int wave = tid >> 6;
  const int wm = wave >> 2;              // code half (16 codes each)
  const int wsl = wave & 3;              // S quarter (128 rows each)
  const int l15 = lane & 15;
  const int lg = lane >> 4;

  f32x4 accL[8], accG[8];
  f32x4 zero = {0.f, 0.f, 0.f, 0.f};
#pragma unroll
  for (int nt = 0; nt < 8; ++nt) { accL[nt] = zero; accG[nt] = zero; }

  // ---- E staging addressing. LDS dest linear: (wave*4+j)*1024 + lane*16.
  // SWZ bits depend only on lane bits 3-4 => j enters linearly (+j*24576 global,
  // +j*1024 LDS). Pre-swizzled global source, linear LDS dest (rule 21).
  {
  }
  const int phys0 = wave * 4096 + lane * 16;
  const int lgo0 = SWZ(phys0);
  const char* eSrc = (const char*)Eb + (size_t)b * S_DIM * 1536
                     + (lgo0 >> 6) * 1536 + (lgo0 & 63);
  char* ldsDest = smem + wave * 4096 + lane * 16;

  // E fragment ds_read base (nt-invariant: SWZ bits from l15 bits 1-2 only).
  const int eBase0 = SWZ((wsl * 128 + l15) * 64 + lg * 16);

  // Q/CW fragment pointers: A-operand row = code = nbase + wm*16 + l15
  const __bf16* qPtr = Qb + (size_t)(nbase + wm * 16 + l15) * D_DIM + lg * 8;
  const __bf16* cPtr = Wb + (size_t)(nbase + wm * 16 + l15) * D_DIM + lg * 8;

#define STAGE(T)                                                                     \
  {                                                                                  \
    const char* s_ = eSrc + (T) * 64;                                                \
    char* d_ = ldsDest + (((T) & 1) << 15);                                          \
    __builtin_amdgcn_global_load_lds((gas1_t)(s_),         (las3_t)(d_),        16, 0, 0); \
    __builtin_amdgcn_global_load_lds((gas1_t)(s_ + 24576), (las3_t)(d_ + 1024), 16, 0, 0); \
    __builtin_amdgcn_global_load_lds((gas1_t)(s_ + 49152), (las3_t)(d_ + 2048), 16, 0, 0); \
    __builtin_amdgcn_global_load_lds((gas1_t)(s_ + 73728), (las3_t)(d_ + 3072), 16, 0, 0); \
  }

  // ---- prologue
  STAGE(0)
  bf16x8 qc = *(const bf16x8*)(qPtr);
  bf16x8 cc = *(const bf16x8*)(cPtr);
  bf16x8 qn, cn;

#pragma unroll 1
  for (int kt = 0; kt < NKCH; ++kt) {
    if (kt < NKCH - 1) {
      qn = *(const bf16x8*)(qPtr + (kt + 1) * 32);
      cn = *(const bf16x8*)(cPtr + (kt + 1) * 32);
      STAGE(kt + 1)
      asm volatile("s_waitcnt vmcnt(6)" ::: "memory");  // drain stage(kt)+B(kt); keep kt+1 in flight
    } else {
      asm volatile("s_waitcnt vmcnt(0)" ::: "memory");
    }
    __builtin_amdgcn_s_barrier();                       // buf kt fully staged for all waves
    __builtin_amdgcn_sched_barrier(0);

    const char* buf = smem + ((kt & 1) << 15);
#pragma unroll
    for (int h = 0; h < 2; ++h) {
      bf16x8 ef[4];
#pragma unroll
      for (int i = 0; i < 4; ++i)
        ef[i] = *(const bf16x8*)(buf + eBase0 + (h * 4 + i) * 1024);
      __builtin_amdgcn_s_setprio(1);
#pragma unroll
      for (int i = 0; i < 4; ++i) {
        accL[h * 4 + i] = __builtin_amdgcn_mfma_f32_16x16x32_bf16(qc, ef[i], accL[h * 4 + i], 0, 0, 0);
        accG[h * 4 + i] = __builtin_amdgcn_mfma_f32_16x16x32_bf16(cc, ef[i], accG[h * 4 + i], 0, 0, 0);
      }
      __builtin_amdgcn_s_setprio(0);
    }
    __builtin_amdgcn_s_barrier();                       // no wave overwrites buf kt^1 early
    qc = qn; cc = cn;
  }
#undef STAGE

  // ---- epilogue: softmax over S per code row + fused logits ------------------
  // lane holds D[code = wm*16 + lg*4 + r][S = wsl*128 + nt*16 + l15]
  const float* brow = bias + b * S_DIM;
  float bval[8];
#pragma unroll
  for (int nt = 0; nt < 8; ++nt) bval[nt] = brow[wsl * 128 + nt * 16 + l15];

  float rmax[4];
#pragma unroll
  for (int r = 0; r < 4; ++r) rmax[r] = -INFINITY;

#pragma unroll
  for (int nt = 0; nt < 8; ++nt)
#pragma unroll
    for (int r = 0; r < 4; ++r) {
      float v = accL[nt][r] + bval[nt];      // 1/sqrt(D) pre-folded into Qb
      accL[nt][r] = v;
      rmax[r] = fmaxf(rmax[r], v);
    }

#pragma unroll
  for (int r = 0; r < 4; ++r) {
    float v = rmax[r];
    v = fmaxf(v, __shfl_xor(v, 1));
    v = fmaxf(v, __shfl_xor(v, 2));
    v = fmaxf(v, __shfl_xor(v, 4));
    v = fmaxf(v, __shfl_xor(v, 8));
    rmax[r] = v;
  }
  if (l15 == 0) {
#pragma unroll
    for (int r = 0; r < 4; ++r) redA[wsl][wm * 16 + lg * 4 + r] = rmax[r];
  }
  __syncthreads();

  float gmax[4];
#pragma unroll
  for (int r = 0; r < 4; ++r) {
    int row = wm * 16 + lg * 4 + r;
    gmax[r] = fmaxf(fmaxf(redA[0][row], redA[1][row]), fmaxf(redA[2][row], redA[3][row]));
  }
  __syncthreads();   // all reads of redA done before reuse

  float rsum[4], pg[4];
#pragma unroll
  for (int r = 0; r < 4; ++r) { rsum[r] = 0.f; pg[r] = 0.f; }

#pragma unroll
  for (int nt = 0; nt < 8; ++nt)
#pragma unroll
    for (int r = 0; r < 4; ++r) {
      float p = __expf(accL[nt][r] - gmax[r]);
      accL[nt][r] = p;
      rsum[r] += p;
      pg[r] += p * accG[nt][r];
    }

#pragma unroll
  for (int r = 0; r < 4; ++r) {
    float s1 = rsum[r], s2 = pg[r];
    s1 += __shfl_xor(s1, 1); s1 += __shfl_xor(s1, 2); s1 += __shfl_xor(s1, 4); s1 += __shfl_xor(s1, 8);
    s2 += __shfl_xor(s2, 1); s2 += __shfl_xor(s2, 2); s2 += __shfl_xor(s2, 4); s2 += __shfl_xor(s2, 8);
    rsum[r] = s1; pg[r] = s2;
  }
  if (l15 == 0) {
#pragma unroll
    for (int r = 0; r < 4; ++r) {
      int row = wm * 16 + lg * 4 + r;
      redA[wsl][row] = rsum[r];
      redB[wsl][row] = pg[r];
    }
  }
  __syncthreads();

  float inv[4];
#pragma unroll
  for (int r = 0; r < 4; ++r) {
    int row = wm * 16 + lg * 4 + r;
    float st = redA[0][row] + redA[1][row] + redA[2][row] + redA[3][row];
    inv[r] = 1.0f / st;
  }

  float* outW = out + (size_t)B_DIM * NC;
#pragma unroll
  for (int r = 0; r < 4; ++r) {
    int gn = nbase + wm * 16 + lg * 4 + r;
    if (gn < NC) {
      size_t base = ((size_t)b * NC + gn) * S_DIM + wsl * 128 + l15;
      float iv = inv[r];
#pragma unroll
      for (int nt = 0; nt < 8; ++nt) outW[base + nt * 16] = accL[nt][r] * iv;
    }
  }

  if (wsl == 0 && l15 == 0) {
#pragma unroll
    for (int r = 0; r < 4; ++r) {
      int row = wm * 16 + lg * 4 + r;
      int gn = nbase + row;
      if (gn < NC) {
        float tot = redB[0][row] + redB[1][row] + redB[2][row] + redB[3][row];
        out[(size_t)b * NC + gn] = tot * inv[r];
      }
    }
  }
}

// ---- fallback (ws too small for bf16 preconversion): f32 reg-staging path
#define FB_TILE 64
#define FB_TILES 140
__launch_bounds__(512, 2)
__global__ void fused_fallback(const float* __restrict__ E32, const float* __restrict__ Q32,
                               const float* __restrict__ W32,
                               const float* __restrict__ bias, float* __restrict__ out) {
  __shared__ __attribute__((aligned(16))) __bf16 sE[S_DIM][40];
  __shared__ __attribute__((aligned(16))) __bf16 sQ[FB_TILE][40];
  __shared__ __attribute__((aligned(16))) __bf16 sC[FB_TILE][40];
  __shared__ float redA[4][FB_TILE];
  __shared__ float redB[4][FB_TILE];

  const int bid = blockIdx.x;
  const int b = bid & 7;
  const int nbase = (bid >> 3) * FB_TILE;
  const int tid = threadIdx.x;
  const int lane = tid & 63;
  const int wave = tid >> 6;
  const int wm = wave >> 2, wsl = wave & 3;
  const int l15 = lane & 15, lg = lane >> 4;

  f32x4 accL[2][8], accG[2][8];
  f32x4 zero = {0.f, 0.f, 0.f, 0.f};
#pragma unroll
  for (int mt = 0; mt < 2; ++mt)
#pragma unroll
    for (int nt = 0; nt < 8; ++nt) { accL[mt][nt] = zero; accG[mt][nt] = zero; }

  const size_t eBase = (size_t)b * S_DIM * D_DIM;

  for (int kt = 0; kt < 24; ++kt) {
    const int k0 = kt * 32;
#pragma unroll
    for (int i = 0; i < 4; ++i) {
      int task = tid + i * 512;
      int s = task >> 2, dg = task & 3;
      const float* sp = E32 + eBase + (size_t)s * D_DIM + k0 + dg * 8;
      float4 a = *reinterpret_cast<const float4*>(sp);
      float4 c = *reinterpret_cast<const float4*>(sp + 4);
      bf16x8 v;
      v[0] = (__bf16)a.x; v[1] = (__bf16)a.y; v[2] = (__bf16)a.z; v[3] = (__bf16)a.w;
      v[4] = (__bf16)c.x; v[5] = (__bf16)c.y; v[6] = (__bf16)c.z; v[7] = (__bf16)c.w;
      *reinterpret_cast<bf16x8*>(&sE[s][dg * 8]) = v;
    }
    {
      int t = tid & 255;
      int r = t >> 2, dg = t & 3;
      int gr = nbase + r;
      bf16x8 v;
      if (gr < NC) {
        const float* sp = ((tid < 256) ? Q32 : W32) + (size_t)gr * D_DIM + k0 + dg * 8;
        float4 a = *reinterpret_cast<const float4*>(sp);
        float4 c = *reinterpret_cast<const float4*>(sp + 4);
        v[0] = (__bf16)a.x; v[1] = (__bf16)a.y; v[2] = (__bf16)a.z; v[3] = (__bf16)a.w;
        v[4] = (__bf16)c.x; v[5] = (__bf16)c.y; v[6] = (__bf16)c.z; v[7] = (__bf16)c.w;
      } else {
#pragma unroll
        for (int j = 0; j < 8; ++j) v[j] = (__bf16)0.0f;
      }
      __bf16* dst = (tid < 256) ? &sQ[r][dg * 8] : &sC[r][dg * 8];
      *reinterpret_cast<bf16x8*>(dst) = v;
    }
    __syncthreads();

    bf16x8 qf0 = *reinterpret_cast<const bf16x8*>(&sQ[wm * 32 + l15][lg * 8]);
    bf16x8 qf1 = *reinterpret_cast<const bf16x8*>(&sQ[wm * 32 + 16 + l15][lg * 8]);
    bf16x8 cf0 = *reinterpret_cast<const bf16x8*>(&sC[wm * 32 + l15][lg * 8]);
    bf16x8 cf1 = *reinterpret_cast<const bf16x8*>(&sC[wm * 32 + 16 + l15][lg * 8]);

#pragma unroll
    for (int nt = 0; nt < 8; ++nt) {
      bf16x8 bf = *reinterpret_cast<const bf16x8*>(&sE[wsl * 128 + nt * 16 + l15][lg * 8]);
      accL[0][nt] = __builtin_amdgcn_mfma_f32_16x16x32_bf16(qf0, bf, accL[0][nt], 0, 0, 0);
      accL[1][nt] = __builtin_amdgcn_mfma_f32_16x16x32_bf16(qf1, bf, accL[1][nt], 0, 0, 0);
      accG[0][nt] = __builtin_amdgcn_mfma_f32_16x16x32_bf16(cf0, bf, accG[0][nt], 0, 0, 0);
      accG[1][nt] = __builtin_amdgcn_mfma_f32_16x16x32_bf16(cf1, bf, accG[1][nt], 0, 0, 0);
    }
    __syncthreads();
  }

  const float scale = 0.036084391824351615f;
  const float* brow = bias + b * S_DIM;
  float bval[8];
#pragma unroll
  for (int nt = 0; nt < 8; ++nt) bval[nt] = brow[wsl * 128 + nt * 16 + l15];

  float rmax[2][4];
#pragma unroll
  for (int mt = 0; mt < 2; ++mt)
#pragma unroll
    for (int r = 0; r < 4; ++r) rmax[mt][r] = -INFINITY;
#pragma unroll
  for (int mt = 0; mt < 2; ++mt)
#pragma unroll
    for (int nt = 0; nt < 8; ++nt)
#pragma unroll
      for (int r = 0; r < 4; ++r) {
        float v = accL[mt][nt][r] * scale + bval[nt];
        accL[mt][nt][r] = v;
        rmax[mt][r] = fmaxf(rmax[mt][r], v);
      }
#pragma unroll
  for (int mt = 0; mt < 2; ++mt)
#pragma unroll
    for (int r = 0; r < 4; ++r) {
      float v = rmax[mt][r];
      v = fmaxf(v, __shfl_xor(v, 1)); v = fmaxf(v, __shfl_xor(v, 2));
      v = fmaxf(v, __shfl_xor(v, 4)); v = fmaxf(v, __shfl_xor(v, 8));
      rmax[mt][r] = v;
    }
  if (l15 == 0) {
#pragma unroll
    for (int mt = 0; mt < 2; ++mt)
#pragma unroll
      for (int r = 0; r < 4; ++r) redA[wsl][wm * 32 + mt * 16 + lg * 4 + r] = rmax[mt][r];
  }
  __syncthreads();
  float gmax[2][4];
#pragma unroll
  for (int mt = 0; mt < 2; ++mt)
#pragma unroll
    for (int r = 0; r < 4; ++r) {
      int row = wm * 32 + mt * 16 + lg * 4 + r;
      gmax[mt][r] = fmaxf(fmaxf(redA[0][row], redA[1][row]), fmaxf(redA[2][row], redA[3][row]));
    }
  __syncthreads();
  float rsum[2][4], pg[2][4];
#pragma unroll
  for (int mt = 0; mt < 2; ++mt)
#pragma unroll
    for (int r = 0; r < 4; ++r) { rsum[mt][r] = 0.f; pg[mt][r] = 0.f; }
#pragma unroll
  for (int mt = 0; mt < 2; ++mt)
#pragma unroll
    for (int nt = 0; nt < 8; ++nt)
#pragma unroll
      for (int r = 0; r < 4; ++r) {
        float p = __expf(accL[mt][nt][r] - gmax[mt][r]);
        accL[mt][nt][r] = p;
        rsum[mt][r] += p;
        pg[mt][r] += p * accG[mt][nt][r];
      }
#pragma unroll
  for (int mt = 0; mt < 2; ++mt)
#pragma unroll
    for (int r = 0; r < 4; ++r) {
      float s1 = rsum[mt][r], s2 = pg[mt][r];
      s1 += __shfl_xor(s1, 1); s1 += __shfl_xor(s1, 2); s1 += __shfl_xor(s1, 4); s1 += __shfl_xor(s1, 8);
      s2 += __shfl_xor(s2, 1); s2 += __shfl_xor(s2, 2); s2 += __shfl_xor(s2, 4); s2 += __shfl_xor(s2, 8);
      rsum[mt][r] = s1; pg[mt][r] = s2;
    }
  if (l15 == 0) {
#pragma unroll
    for (int mt = 0; mt < 2; ++mt)
#pragma unroll
      for (int r = 0; r < 4; ++r) {
        int row = wm * 32 + mt * 16 + lg * 4 + r;
        redA[wsl][row] = rsum[mt][r];
        redB[wsl][row] = pg[mt][r];
      }
  }
  __syncthreads();
  float inv[2][4];
#pragma unroll
  for (int mt = 0; mt < 2; ++mt)
#pragma unroll
    for (int r = 0; r < 4; ++r) {
      int row = wm * 32 + mt * 16 + lg * 4 + r;
      float st = redA[0][row] + redA[1][row] + redA[2][row] + redA[3][row];
      inv[mt][r] = 1.0f / st;
    }
  float* outW = out + (size_t)B_DIM * NC;
#pragma unroll
  for (int mt = 0; mt < 2; ++mt)
#pragma unroll
    for (int r = 0; r < 4; ++r) {
      int gn = nbase + wm * 32 + mt * 16 + lg * 4 + r;
      if (gn < NC) {
        size_t base = ((size_t)b * NC + gn) * S_DIM + wsl * 128 + l15;
        float iv = inv[mt][r];
#pragma unroll
        for (int nt = 0; nt < 8; ++nt) outW[base + nt * 16] = accL[mt][nt][r] * iv;
      }
    }
  if (wsl == 0 && l15 == 0) {
#pragma unroll
    for (int mt = 0; mt < 2; ++mt)
#pragma unroll
      for (int r = 0; r < 4; ++r) {
        int row = wm * 32 + mt * 16 + lg * 4 + r;
        int gn = nbase + row;
        if (gn < NC) {
          float tot = redB[0][row] + redB[1][row] + redB[2][row] + redB[3][row];
          out[(size_t)b * NC + gn] = tot * inv[mt][r];
        }
      }
  }
}

extern "C" void kernel_launch(void* const* d_in, const int* in_sizes, int n_in,
                              void* d_out, int out_size, void* d_ws, size_t ws_size,
                              hipStream_t stream) {
  const float* E32 = (const float*)d_in[0];
  const unsigned char* mraw = (const unsigned char*)d_in[1];
  const float* Q32 = (const float*)d_in[2];
  const float* W32 = (const float*)d_in[3];
  float* out = (float*)d_out;

  char* ws = (char*)d_ws;
  float* bias = (float*)ws;
  __bf16* Eb = (__bf16*)(ws + MASK_BYTES);
  __bf16* Qb = (__bf16*)(ws + MASK_BYTES + (size_t)B_DIM * S_DIM * D_DIM * 2);
  __bf16* Wb = (__bf16*)((char*)Qb + (size_t)N_PAD * D_DIM * 2);
  size_t need = MASK_BYTES + (size_t)B_DIM * S_DIM * D_DIM * 2 + 2 * (size_t)N_PAD * D_DIM * 2;
  int preconv = (ws_size >= need) ? 1 : 0;

  prep_mask_kernel<<<1, 256, 0, stream>>>(mraw, bias);

  if (preconv) {
    long nE = (long)B_DIM * S_DIM * D_DIM;
    cvt_kernel<<<(int)(nE / 8 / 256), 256, 0, stream>>>(E32, Eb, nE, 1.0f);
    long nQ = (long)NC * D_DIM;
    long nQp = (long)N_PAD * D_DIM;
    // fold 1/sqrt(D) into Q
    cvt_kernel<<<(int)(nQp / 8 / 256), 256, 0, stream>>>(Q32, Qb, nQ, 0.036084391824351615f);
    cvt_kernel<<<(int)(nQp / 8 / 256), 256, 0, stream>>>(W32, Wb, nQ, 1.0f);
    fused_kernel<<<N_TILES * B_DIM, 512, 0, stream>>>(Eb, Qb, Wb, bias, out);
  } else {
    fused_fallback<<<FB_TILES * B_DIM, 512, 0, stream>>>(E32, Q32, W32, bias, out);
  }
}

// Round 7
// 258.476 us; speedup vs baseline: 3.4145x; 1.0082x over previous
//
#include <hip/hip_runtime.h>
#include <hip/hip_bf16.h>
#include <math.h>

typedef __bf16 bf16x8 __attribute__((ext_vector_type(8)));
typedef float f32x4 __attribute__((ext_vector_type(4)));

#define B_DIM 8
#define S_DIM 512
#define D_DIM 768
#define NC 8921
#define N_PAD 8960
#define TILE_N 64
#define N_TILES 140
#define KT 12              // K tiles of 64 elements (128 B rows)
#define MASK_BYTES 16384

typedef const __attribute__((address_space(1))) void* gas1_t;
typedef __attribute__((address_space(3))) void* las3_t;

// ---- mask prep: sniff dtype (bool8 / int32 / float32) and emit 0/-inf bias
__global__ void prep_mask_kernel(const unsigned char* __restrict__ raw, float* __restrict__ bias) {
  __shared__ int s_ms, s_f32;
  int tid = threadIdx.x;
  if (tid == 0) { s_ms = 0; s_f32 = 0; }
  __syncthreads();
  int ms = 0, f32c = 0;
  for (int i = tid; i < B_DIM * S_DIM; i += 256) {
    unsigned char c = raw[i];
    if ((i & 3) != 0 && c != 0) ms++;
    if ((i & 3) == 3 && c == 0x3F) f32c++;
  }
  atomicAdd(&s_ms, ms);
  atomicAdd(&s_f32, f32c);
  __syncthreads();
  int mode = (s_ms == 0) ? 0 : ((s_f32 > 500) ? 2 : 1);
  for (int i = tid; i < B_DIM * S_DIM; i += 256) {
    bool m;
    if (mode == 0)      m = ((const int*)raw)[i] != 0;
    else if (mode == 1) m = raw[i] != 0;
    else                m = ((const float*)raw)[i] != 0.0f;
    bias[i] = m ? 0.0f : -INFINITY;
  }
}

// ---- f32 -> bf16 conversion (times scale) with zero padding past nvalid
__global__ void cvt_kernel(const float* __restrict__ src, __bf16* __restrict__ dst,
                           long nvalid, float scale) {
  long i = ((long)blockIdx.x * blockDim.x + threadIdx.x) * 8;
  bf16x8 o;
  if (i + 8 <= nvalid) {
    float4 a = *reinterpret_cast<const float4*>(src + i);
    float4 b = *reinterpret_cast<const float4*>(src + i + 4);
    o[0] = (__bf16)(a.x * scale); o[1] = (__bf16)(a.y * scale);
    o[2] = (__bf16)(a.z * scale); o[3] = (__bf16)(a.w * scale);
    o[4] = (__bf16)(b.x * scale); o[5] = (__bf16)(b.y * scale);
    o[6] = (__bf16)(b.z * scale); o[7] = (__bf16)(b.w * scale);
  } else {
#pragma unroll
    for (int j = 0; j < 8; ++j) o[j] = (__bf16)0.0f;
  }
  *reinterpret_cast<bf16x8*>(dst + i) = o;
}

// ---- main fused kernel: 64 codes x 512 S per block, BK=64, m201-style
//      8-phase schedule: counted vmcnt(8) (never drained mid-loop), per-phase
//      {4 swizzled ds_read_b128 | 2 A-prefetch | barrier | 16 MFMA | barrier}.
__launch_bounds__(512, 2)
__global__ void fused_kernel(const __bf16* __restrict__ Eb, const __bf16* __restrict__ Qb,
                             const __bf16* __restrict__ Wb, const float* __restrict__ bias,
                             float* __restrict__ out) {
  __shared__ __attribute__((aligned(16))) char smem[2 * 65536];   // E dbuf, 64KB each
  __shared__ float redA[4][TILE_N];
  __shared__ float redB[4][TILE_N];

  const int bid = blockIdx.x;
  const int b = bid & 7;                 // batch == XCD -> E slice L2-resident
  const int nbase = (bid >> 3) * TILE_N;
  const int tid = threadIdx.x;
  const int lane = tid & 63;
  const int w = tid >> 6;
  const int wm = w >> 2;                 // code half (32 codes)
  const int wsl = w & 3;                 // S quarter (128 rows)
  const int l15 = lane & 15;
  const int lg = lane >> 4;

  f32x4 accL[2][8], accG[2][8];
  f32x4 zero = {0.f, 0.f, 0.f, 0.f};
#pragma unroll
  for (int mt = 0; mt < 2; ++mt)
#pragma unroll
    for (int nt = 0; nt < 8; ++nt) { accL[mt][nt] = zero; accG[mt][nt] = zero; }

  // ---- E staging addressing (rule 21: linear LDS dest, inverse-swz source).
  // Wave w stages rows [w*64, w*64+64). Instr j: rows 8j..8j+7; lane l ->
  // row 8j+(l>>3), 16B slot (l&7)^(l>>3). LDS byte(row,slot') = row*128+slot'*16.
  const char* eSrc = (const char*)Eb + (size_t)b * S_DIM * 1536
      + ((size_t)w * 64 + (lane >> 3)) * 1536
      + (((lane & 7) ^ (lane >> 3)) * 16);
  const int ldsWB = w * 8192;            // wave dest base (wave-uniform)

  // ds_read offsets: row = wsl*128 + nt*16 + l15, slot = (kh*4+lg)^(l15&7)
  int eOffK[2];
#pragma unroll
  for (int kh = 0; kh < 2; ++kh)
    eOffK[kh] = (wsl * 128 + l15) * 128 + ((((kh << 2) | lg) ^ (l15 & 7)) << 4);

  // A-operand (Q/CW) row pointers: code = nbase + wm*32 + mt*16 + l15
  const __bf16* qPtr = Qb + (size_t)(nbase + wm * 32 + l15) * D_DIM + lg * 8;
  const __bf16* cPtr = Wb + (size_t)(nbase + wm * 32 + l15) * D_DIM + lg * 8;

  bf16x8 q0[2][2], c0[2][2], q1[2][2], c1[2][2];  // A-frag double buffer (static idx)

#define STAGE8(T, PAR)                                                                    \
  {                                                                                       \
    const char* s_ = eSrc + (T) * 128;                                                    \
    _Pragma("unroll")                                                                     \
    for (int j = 0; j < 8; ++j)                                                           \
      __builtin_amdgcn_global_load_lds((gas1_t)(s_ + j * 12288),                          \
          (las3_t)(smem + (PAR) * 65536 + ldsWB + j * 1024), 16, 0, 0);                   \
  }

#define ALOAD(DST, ARR, PTR, T)                                                           \
  { DST[0] = *(const bf16x8*)(PTR + (size_t)ARR * 12288 + (T) * 64);                      \
    DST[1] = *(const bf16x8*)(PTR + (size_t)ARR * 12288 + (T) * 64 + 32); }

  // ---- prologue: A(0) into set0, stage tile 0 into buf 0
  ALOAD(q0[0], 0, qPtr, 0) ALOAD(q0[1], 1, qPtr, 0)
  ALOAD(c0[0], 0, cPtr, 0) ALOAD(c0[1], 1, cPtr, 0)
  STAGE8(0, 0)

#define KTILE(T, PAR, CQ, CC, NQ, NCW, ISLAST)                                            \
  {                                                                                       \
    if (!(ISLAST)) {                                                                      \
      STAGE8((T) + 1, 1 - (PAR))                                                          \
      asm volatile("s_waitcnt vmcnt(8)" ::: "memory");                                    \
    } else {                                                                              \
      asm volatile("s_waitcnt vmcnt(0)" ::: "memory");                                    \
    }                                                                                     \
    __builtin_amdgcn_s_barrier();                                                         \
    __builtin_amdgcn_sched_barrier(0);                                                    \
    const char* buf_ = smem + (PAR) * 65536;                                              \
    _Pragma("unroll")                                                                     \
    for (int p = 0; p < 4; ++p) {                                                         \
      bf16x8 ef[2][2];                                                                    \
      _Pragma("unroll")                                                                   \
      for (int i = 0; i < 2; ++i)                                                         \
        _Pragma("unroll")                                                                 \
        for (int kh = 0; kh < 2; ++kh)                                                    \
          ef[i][kh] = *(const bf16x8*)(buf_ + (2 * p + i) * 2048 + eOffK[kh]);            \
      if (!(ISLAST)) {                                                                    \
        if (p == 0) { ALOAD(NQ[0], 0, qPtr, (T) + 1) }                                    \
        if (p == 1) { ALOAD(NQ[1], 1, qPtr, (T) + 1) }                                    \
        if (p == 2) { ALOAD(NCW[0], 0, cPtr, (T) + 1) }                                   \
        if (p == 3) { ALOAD(NCW[1], 1, cPtr, (T) + 1) }                                   \
      }                                                                                   \
      __builtin_amdgcn_s_barrier();                                                       \
      __builtin_amdgcn_sched_barrier(0);                                                  \
      __builtin_amdgcn_s_setprio(1);                                                      \
      _Pragma("unroll")                                                                   \
      for (int i = 0; i < 2; ++i)                                                         \
        _Pragma("unroll")                                                                 \
        for (int kh = 0; kh < 2; ++kh) {                                                  \
          accL[0][2 * p + i] = __builtin_amdgcn_mfma_f32_16x16x32_bf16(CQ[0][kh], ef[i][kh], accL[0][2 * p + i], 0, 0, 0); \
          accL[1][2 * p + i] = __builtin_amdgcn_mfma_f32_16x16x32_bf16(CQ[1][kh], ef[i][kh], accL[1][2 * p + i], 0, 0, 0); \
          accG[0][2 * p + i] = __builtin_amdgcn_mfma_f32_16x16x32_bf16(CC[0][kh], ef[i][kh], accG[0][2 * p + i], 0, 0, 0); \
          accG[1][2 * p + i] = __builtin_amdgcn_mfma_f32_16x16x32_bf16(CC[1][kh], ef[i][kh], accG[1][2 * p + i], 0, 0, 0); \
        }                                                                                 \
      __builtin_amdgcn_s_setprio(0);                                                      \
      __builtin_amdgcn_s_barrier();                                                       \
    }                                                                                     \
  }

#pragma unroll 1
  for (int tp = 0; tp < 5; ++tp) {
    KTILE(tp * 2,     0, q0, c0, q1, c1, 0)
    KTILE(tp * 2 + 1, 1, q1, c1, q0, c0, 0)
  }
  KTILE(10, 0, q0, c0, q1, c1, 0)
  KTILE(11, 1, q1, c1, q0, c0, 1)
#undef KTILE
#undef STAGE8
#undef ALOAD

  // ---- epilogue: softmax over S per code row + fused logits (r2-verified) ----
  const float* brow = bias + b * S_DIM;
  float bval[8];
#pragma unroll
  for (int nt = 0; nt < 8; ++nt) bval[nt] = brow[wsl * 128 + nt * 16 + l15];

  float rmax[2][4];
#pragma unroll
  for (int mt = 0; mt < 2; ++mt)
#pragma unroll
    for (int r = 0; r < 4; ++r) rmax[mt][r] = -INFINITY;

#pragma unroll
  for (int mt = 0; mt < 2; ++mt)
#pragma unroll
    for (int nt = 0; nt < 8; ++nt)
#pragma unroll
      for (int r = 0; r < 4; ++r) {
        float v = accL[mt][nt][r] + bval[nt];   // 1/sqrt(D) pre-folded into Qb
        accL[mt][nt][r] = v;
        rmax[mt][r] = fmaxf(rmax[mt][r], v);
      }

#pragma unroll
  for (int mt = 0; mt < 2; ++mt)
#pragma unroll
    for (int r = 0; r < 4; ++r) {
      float v = rmax[mt][r];
      v = fmaxf(v, __shfl_xor(v, 1));
      v = fmaxf(v, __shfl_xor(v, 2));
      v = fmaxf(v, __shfl_xor(v, 4));
      v = fmaxf(v, __shfl_xor(v, 8));
      rmax[mt][r] = v;
    }
  if (l15 == 0) {
#pragma unroll
    for (int mt = 0; mt < 2; ++mt)
#pragma unroll
      for (int r = 0; r < 4; ++r) redA[wsl][wm * 32 + mt * 16 + lg * 4 + r] = rmax[mt][r];
  }
  __syncthreads();

  float gmax[2][4];
#pragma unroll
  for (int mt = 0; mt < 2; ++mt)
#pragma unroll
    for (int r = 0; r < 4; ++r) {
      int row = wm * 32 + mt * 16 + lg * 4 + r;
      gmax[mt][r] = fmaxf(fmaxf(redA[0][row], redA[1][row]), fmaxf(redA[2][row], redA[3][row]));
    }
  __syncthreads();

  float rsum[2][4], pg[2][4];
#pragma unroll
  for (int mt = 0; mt < 2; ++mt)
#pragma unroll
    for (int r = 0; r < 4; ++r) { rsum[mt][r] = 0.f; pg[mt][r] = 0.f; }

#pragma unroll
  for (int mt = 0; mt < 2; ++mt)
#pragma unroll
    for (int nt = 0; nt < 8; ++nt)
#pragma unroll
      for (int r = 0; r < 4; ++r) {
        float p = __expf(accL[mt][nt][r] - gmax[mt][r]);
        accL[mt][nt][r] = p;
        rsum[mt][r] += p;
        pg[mt][r] += p * accG[mt][nt][r];
      }

#pragma unroll
  for (int mt = 0; mt < 2; ++mt)
#pragma unroll
    for (int r = 0; r < 4; ++r) {
      float s1 = rsum[mt][r], s2 = pg[mt][r];
      s1 += __shfl_xor(s1, 1); s1 += __shfl_xor(s1, 2); s1 += __shfl_xor(s1, 4); s1 += __shfl_xor(s1, 8);
      s2 += __shfl_xor(s2, 1); s2 += __shfl_xor(s2, 2); s2 += __shfl_xor(s2, 4); s2 += __shfl_xor(s2, 8);
      rsum[mt][r] = s1; pg[mt][r] = s2;
    }
  if (l15 == 0) {
#pragma unroll
    for (int mt = 0; mt < 2; ++mt)
#pragma unroll
      for (int r = 0; r < 4; ++r) {
        int row = wm * 32 + mt * 16 + lg * 4 + r;
        redA[wsl][row] = rsum[mt][r];
        redB[wsl][row] = pg[mt][r];
      }
  }
  __syncthreads();

  float inv[2][4];
#pragma unroll
  for (int mt = 0; mt < 2; ++mt)
#pragma unroll
    for (int r = 0; r < 4; ++r) {
      int row = wm * 32 + mt * 16 + lg * 4 + r;
      float st = redA[0][row] + redA[1][row] + redA[2][row] + redA[3][row];
      inv[mt][r] = 1.0f / st;
    }

  float* outW = out + (size_t)B_DIM * NC;
#pragma unroll
  for (int mt = 0; mt < 2; ++mt)
#pragma unroll
    for (int r = 0; r < 4; ++r) {
      int gn = nbase + wm * 32 + mt * 16 + lg * 4 + r;
      if (gn < NC) {
        size_t base = ((size_t)b * NC + gn) * S_DIM + wsl * 128 + l15;
        float iv = inv[mt][r];
#pragma unroll
        for (int nt = 0; nt < 8; ++nt) outW[base + nt * 16] = accL[mt][nt][r] * iv;
      }
    }

  if (wsl == 0 && l15 == 0) {
#pragma unroll
    for (int mt = 0; mt < 2; ++mt)
#pragma unroll
      for (int r = 0; r < 4; ++r) {
        int row = wm * 32 + mt * 16 + lg * 4 + r;
        int gn = nbase + row;
        if (gn < NC) {
          float tot = redB[0][row] + redB[1][row] + redB[2][row] + redB[3][row];
          out[(size_t)b * NC + gn] = tot * inv[mt][r];
        }
      }
  }
}

// ---- fallback (ws too small for bf16 preconversion): f32 reg-staging path
#define FB_TILE 64
#define FB_TILES 140
__launch_bounds__(512, 2)
__global__ void fused_fallback(const float* __restrict__ E32, const float* __restrict__ Q32,
                               const float* __restrict__ W32,
                               const float* __restrict__ bias, float* __restrict__ out) {
  __shared__ __attribute__((aligned(16))) __bf16 sE[S_DIM][40];
  __shared__ __attribute__((aligned(16))) __bf16 sQ[FB_TILE][40];
  __shared__ __attribute__((aligned(16))) __bf16 sC[FB_TILE][40];
  __shared__ float redA[4][FB_TILE];
  __shared__ float redB[4][FB_TILE];

  const int bid = blockIdx.x;
  const int b = bid & 7;
  const int nbase = (bid >> 3) * FB_TILE;
  const int tid = threadIdx.x;
  const int lane = tid & 63;
  const int wave = tid >> 6;
  const int wm = wave >> 2, wsl = wave & 3;
  const int l15 = lane & 15, lg = lane >> 4;

  f32x4 accL[2][8], accG[2][8];
  f32x4 zero = {0.f, 0.f, 0.f, 0.f};
#pragma unroll
  for (int mt = 0; mt < 2; ++mt)
#pragma unroll
    for (int nt = 0; nt < 8; ++nt) { accL[mt][nt] = zero; accG[mt][nt] = zero; }

  const size_t eBase = (size_t)b * S_DIM * D_DIM;

  for (int kt = 0; kt < 24; ++kt) {
    const int k0 = kt * 32;
#pragma unroll
    for (int i = 0; i < 4; ++i) {
      int task = tid + i * 512;
      int s = task >> 2, dg = task & 3;
      const float* sp = E32 + eBase + (size_t)s * D_DIM + k0 + dg * 8;
      float4 a = *reinterpret_cast<const float4*>(sp);
      float4 c = *reinterpret_cast<const float4*>(sp + 4);
      bf16x8 v;
      v[0] = (__bf16)a.x; v[1] = (__bf16)a.y; v[2] = (__bf16)a.z; v[3] = (__bf16)a.w;
      v[4] = (__bf16)c.x; v[5] = (__bf16)c.y; v[6] = (__bf16)c.z; v[7] = (__bf16)c.w;
      *reinterpret_cast<bf16x8*>(&sE[s][dg * 8]) = v;
    }
    {
      int t = tid & 255;
      int r = t >> 2, dg = t & 3;
      int gr = nbase + r;
      bf16x8 v;
      if (gr < NC) {
        const float* sp = ((tid < 256) ? Q32 : W32) + (size_t)gr * D_DIM + k0 + dg * 8;
        float4 a = *reinterpret_cast<const float4*>(sp);
        float4 c = *reinterpret_cast<const float4*>(sp + 4);
        v[0] = (__bf16)a.x; v[1] = (__bf16)a.y; v[2] = (__bf16)a.z; v[3] = (__bf16)a.w;
        v[4] = (__bf16)c.x; v[5] = (__bf16)c.y; v[6] = (__bf16)c.z; v[7] = (__bf16)c.w;
      } else {
#pragma unroll
        for (int j = 0; j < 8; ++j) v[j] = (__bf16)0.0f;
      }
      __bf16* dst = (tid < 256) ? &sQ[r][dg * 8] : &sC[r][dg * 8];
      *reinterpret_cast<bf16x8*>(dst) = v;
    }
    __syncthreads();

    bf16x8 qf0 = *reinterpret_cast<const bf16x8*>(&sQ[wm * 32 + l15][lg * 8]);
    bf16x8 qf1 = *reinterpret_cast<const bf16x8*>(&sQ[wm * 32 + 16 + l15][lg * 8]);
    bf16x8 cf0 = *reinterpret_cast<const bf16x8*>(&sC[wm * 32 + l15][lg * 8]);
    bf16x8 cf1 = *reinterpret_cast<const bf16x8*>(&sC[wm * 32 + 16 + l15][lg * 8]);

#pragma unroll
    for (int nt = 0; nt < 8; ++nt) {
      bf16x8 bf = *reinterpret_cast<const bf16x8*>(&sE[wsl * 128 + nt * 16 + l15][lg * 8]);
      accL[0][nt] = __builtin_amdgcn_mfma_f32_16x16x32_bf16(qf0, bf, accL[0][nt], 0, 0, 0);
      accL[1][nt] = __builtin_amdgcn_mfma_f32_16x16x32_bf16(qf1, bf, accL[1][nt], 0, 0, 0);
      accG[0][nt] = __builtin_amdgcn_mfma_f32_16x16x32_bf16(cf0, bf, accG[0][nt], 0, 0, 0);
      accG[1][nt] = __builtin_amdgcn_mfma_f32_16x16x32_bf16(cf1, bf, accG[1][nt], 0, 0, 0);
    }
    __syncthreads();
  }

  const float scale = 0.036084391824351615f;
  const float* brow = bias + b * S_DIM;
  float bval[8];
#pragma unroll
  for (int nt = 0; nt < 8; ++nt) bval[nt] = brow[wsl * 128 + nt * 16 + l15];

  float rmax[2][4];
#pragma unroll
  for (int mt = 0; mt < 2; ++mt)
#pragma unroll
    for (int r = 0; r < 4; ++r) rmax[mt][r] = -INFINITY;
#pragma unroll
  for (int mt = 0; mt < 2; ++mt)
#pragma unroll
    for (int nt = 0; nt < 8; ++nt)
#pragma unroll
      for (int r = 0; r < 4; ++r) {
        float v = accL[mt][nt][r] * scale + bval[nt];
        accL[mt][nt][r] = v;
        rmax[mt][r] = fmaxf(rmax[mt][r], v);
      }
#pragma unroll
  for (int mt = 0; mt < 2; ++mt)
#pragma unroll
    for (int r = 0; r < 4; ++r) {
      float v = rmax[mt][r];
      v = fmaxf(v, __shfl_xor(v, 1)); v = fmaxf(v, __shfl_xor(v, 2));
      v = fmaxf(v, __shfl_xor(v, 4)); v = fmaxf(v, __shfl_xor(v, 8));
      rmax[mt][r] = v;
    }
  if (l15 == 0) {
#pragma unroll
    for (int mt = 0; mt < 2; ++mt)
#pragma unroll
      for (int r = 0; r < 4; ++r) redA[wsl][wm * 32 + mt * 16 + lg * 4 + r] = rmax[mt][r];
  }
  __syncthreads();
  float gmax[2][4];
#pragma unroll
  for (int mt = 0; mt < 2; ++mt)
#pragma unroll
    for (int r = 0; r < 4; ++r) {
      int row = wm * 32 + mt * 16 + lg * 4 + r;
      gmax[mt][r] = fmaxf(fmaxf(redA[0][row], redA[1][row]), fmaxf(redA[2][row], redA[3][row]));
    }
  __syncthreads();
  float rsum[2][4], pg[2][4];
#pragma unroll
  for (int mt = 0; mt < 2; ++mt)
#pragma unroll
    for (int r = 0; r < 4; ++r) { rsum[mt][r] = 0.f; pg[mt][r] = 0.f; }
#pragma unroll
  for (int mt = 0; mt < 2; ++mt)
#pragma unroll
    for (int nt = 0; nt < 8; ++nt)
#pragma unroll
      for (int r = 0; r < 4; ++r) {
        float p = __expf(accL[mt][nt][r] - gmax[mt][r]);
        accL[mt][nt][r] = p;
        rsum[mt][r] += p;
        pg[mt][r] += p * accG[mt][nt][r];
      }
#pragma unroll
  for (int mt = 0; mt < 2; ++mt)
#pragma unroll
    for (int r = 0; r < 4; ++r) {
      float s1 = rsum[mt][r], s2 = pg[mt][r];
      s1 += __shfl_xor(s1, 1); s1 += __shfl_xor(s1, 2); s1 += __shfl_xor(s1, 4); s1 += __shfl_xor(s1, 8);
      s2 += __shfl_xor(s2, 1); s2 += __shfl_xor(s2, 2); s2 += __shfl_xor(s2, 4); s2 += __shfl_xor(s2, 8);
      rsum[mt][r] = s1; pg[mt][r] = s2;
    }
  if (l15 == 0) {
#pragma unroll
    for (int mt = 0; mt < 2; ++mt)
#pragma unroll
      for (int r = 0; r < 4; ++r) {
        int row = wm * 32 + mt * 16 + lg * 4 + r;
        redA[wsl][row] = rsum[mt][r];
        redB[wsl][row] = pg[mt][r];
      }
  }
  __syncthreads();
  float inv[2][4];
#pragma unroll
  for (int mt = 0; mt < 2; ++mt)
#pragma unroll
    for (int r = 0; r < 4; ++r) {
      int row = wm * 32 + mt * 16 + lg * 4 + r;
      float st = redA[0][row] + redA[1][row] + redA[2][row] + redA[3][row];
      inv[mt][r] = 1.0f / st;
    }
  float* outW = out + (size_t)B_DIM * NC;
#pragma unroll
  for (int mt = 0; mt < 2; ++mt)
#pragma unroll
    for (int r = 0; r < 4; ++r) {
      int gn = nbase + wm * 32 + mt * 16 + lg * 4 + r;
      if (gn < NC) {
        size_t base = ((size_t)b * NC + gn) * S_DIM + wsl * 128 + l15;
        float iv = inv[mt][r];
#pragma unroll
        for (int nt = 0; nt < 8; ++nt) outW[base + nt * 16] = accL[mt][nt][r] * iv;
      }
    }
  if (wsl == 0 && l15 == 0) {
#pragma unroll
    for (int mt = 0; mt < 2; ++mt)
#pragma unroll
      for (int r = 0; r < 4; ++r) {
        int row = wm * 32 + mt * 16 + lg * 4 + r;
        int gn = nbase + row;
        if (gn < NC) {
          float tot = redB[0][row] + redB[1][row] + redB[2][row] + redB[3][row];
          out[(size_t)b * NC + gn] = tot * inv[mt][r];
        }
      }
  }
}

extern "C" void kernel_launch(void* const* d_in, const int* in_sizes, int n_in,
                              void* d_out, int out_size, void* d_ws, size_t ws_size,
                              hipStream_t stream) {
  const float* E32 = (const float*)d_in[0];
  const unsigned char* mraw = (const unsigned char*)d_in[1];
  const float* Q32 = (const float*)d_in[2];
  const float* W32 = (const float*)d_in[3];
  float* out = (float*)d_out;

  char* ws = (char*)d_ws;
  float* bias = (float*)ws;
  __bf16* Eb = (__bf16*)(ws + MASK_BYTES);
  __bf16* Qb = (__bf16*)(ws + MASK_BYTES + (size_t)B_DIM * S_DIM * D_DIM * 2);
  __bf16* Wb = (__bf16*)((char*)Qb + (size_t)N_PAD * D_DIM * 2);
  size_t need = MASK_BYTES + (size_t)B_DIM * S_DIM * D_DIM * 2 + 2 * (size_t)N_PAD * D_DIM * 2;
  int preconv = (ws_size >= need) ? 1 : 0;

  prep_mask_kernel<<<1, 256, 0, stream>>>(mraw, bias);

  if (preconv) {
    long nE = (long)B_DIM * S_DIM * D_DIM;
    cvt_kernel<<<(int)(nE / 8 / 256), 256, 0, stream>>>(E32, Eb, nE, 1.0f);
    long nQ = (long)NC * D_DIM;
    long nQp = (long)N_PAD * D_DIM;
    // fold 1/sqrt(D) into Q
    cvt_kernel<<<(int)(nQp / 8 / 256), 256, 0, stream>>>(Q32, Qb, nQ, 0.036084391824351615f);
    cvt_kernel<<<(int)(nQp / 8 / 256), 256, 0, stream>>>(W32, Wb, nQ, 1.0f);
    fused_kernel<<<N_TILES * B_DIM, 512, 0, stream>>>(Eb, Qb, Wb, bias, out);
  } else {
    fused_fallback<<<FB_TILES * B_DIM, 512, 0, stream>>>(E32, Q32, W32, bias, out);
  }
}